// Round 2
// baseline (1183.111 us; speedup 1.0000x reference)
//
#include <hip/hip_runtime.h>
#include <hip/hip_bf16.h>

#define WPB 4  // waves per block

static __device__ __forceinline__ float wred(float v) {
#pragma unroll
  for (int o = 32; o > 0; o >>= 1) v += __shfl_xor(v, o, 64);
  return v;
}

// h0[n,d] = x[n,:8] @ node_W[:,d] + node_b[d]
__global__ void node_enc_kernel(const float* __restrict__ x, const float* __restrict__ W,
                                const float* __restrict__ b, float* __restrict__ z, int N) {
  int t = blockIdx.x * blockDim.x + threadIdx.x;
  if (t >= N * 64) return;
  int n = t >> 6, d = t & 63;
  float acc = b[d];
#pragma unroll
  for (int k = 0; k < 8; ++k) acc = fmaf(x[n * 8 + k], W[k * 64 + d], acc);
  z[t] = acc;
}

__global__ void hist_kernel(const int* __restrict__ dst, int* __restrict__ cnt, int E) {
  int e = blockIdx.x * blockDim.x + threadIdx.x;
  if (e < E) atomicAdd(&cnt[dst[e]], 1);
}

// exclusive scan of cnt[0..n) -> off[0..n], single block of 1024
__global__ void scan_kernel(const int* __restrict__ cnt, int* __restrict__ off, int n) {
  __shared__ int lds[1024];
  int tid = threadIdx.x;
  int carry = 0;
  for (int base = 0; base < n; base += 1024) {
    int i = base + tid;
    int v = (i < n) ? cnt[i] : 0;
    lds[tid] = v;
    __syncthreads();
    for (int ofs = 1; ofs < 1024; ofs <<= 1) {
      int tv = (tid >= ofs) ? lds[tid - ofs] : 0;
      __syncthreads();
      lds[tid] += tv;
      __syncthreads();
    }
    if (i < n) off[i] = carry + lds[tid] - v;
    int total = lds[1023];
    __syncthreads();
    carry += total;
  }
  if (tid == 0) off[n] = carry;
}

__global__ void scatter_kernel(const int* __restrict__ src, const int* __restrict__ dst,
                               const int* __restrict__ off, int* __restrict__ cur,
                               int* __restrict__ csr_src, int* __restrict__ csr_edge, int E) {
  int e = blockIdx.x * blockDim.x + threadIdx.x;
  if (e >= E) return;
  int dn = dst[e];
  int pos = atomicAdd(&cur[dn], 1);
  int idx = off[dn] + pos;
  csr_src[idx] = src[e];
  csr_edge[idx] = e;
}

// z = relu(LN(h; g, b)), one wave per node, lane = channel
__global__ void preln_kernel(const float* __restrict__ h, float* __restrict__ z,
                             const float* __restrict__ g, const float* __restrict__ b, int N) {
  int wv = threadIdx.x >> 6, ln = threadIdx.x & 63;
  int n = blockIdx.x * WPB + wv;
  if (n >= N) return;
  float v = h[n * 64 + ln];
  float mu = wred(v) * (1.f / 64.f);
  float dd = v - mu;
  float var = wred(dd * dd) * (1.f / 64.f);
  float r = rsqrtf(var + 1e-5f);
  z[n * 64 + ln] = fmaxf(dd * r * g[ln] + b[ln], 0.f);
}

// One wave per node: online-softmax aggregation over in-edges + fused 64->128->64 MLP.
template <int RESID>
__global__ void conv_kernel(const float* __restrict__ zbuf, float* __restrict__ hbuf,
                            const int* __restrict__ off, const int* __restrict__ csr_src,
                            const int* __restrict__ csr_edge, const float* __restrict__ edge_attr,
                            const float* __restrict__ edge_W, const float* __restrict__ edge_b,
                            const float* __restrict__ tptr, int layer,
                            const float* __restrict__ W1, const float* __restrict__ b1,
                            const float* __restrict__ g1, const float* __restrict__ bb1,
                            const float* __restrict__ W2, const float* __restrict__ b2, int N) {
  __shared__ float sh[WPB][128];
  int wv = threadIdx.x >> 6, d = threadIdx.x & 63;
  int n = blockIdx.x * WPB + wv;
  if (n >= N) return;
  float eW[8];
#pragma unroll
  for (int k = 0; k < 8; ++k) eW[k] = edge_W[k * 64 + d];
  float ebd = edge_b[d];
  float tval = tptr[layer];
  float zn = zbuf[n * 64 + d];
  int beg = off[n], end = off[n + 1];
  float m = -__builtin_inff(), s = 0.f, w = 0.f;
  for (int i = beg; i < end; ++i) {
    int sn = csr_src[i];
    int e = csr_edge[i];
    float zs = zbuf[(size_t)sn * 64 + d];
    const float4* ap = reinterpret_cast<const float4*>(edge_attr + (size_t)e * 8);
    float4 a0 = ap[0], a1 = ap[1];
    float ea = ebd;
    ea = fmaf(a0.x, eW[0], ea); ea = fmaf(a0.y, eW[1], ea);
    ea = fmaf(a0.z, eW[2], ea); ea = fmaf(a0.w, eW[3], ea);
    ea = fmaf(a1.x, eW[4], ea); ea = fmaf(a1.y, eW[5], ea);
    ea = fmaf(a1.z, eW[6], ea); ea = fmaf(a1.w, eW[7], ea);
    float msg = fmaxf(zs + ea, 0.f) + 1e-7f;
    float logit = msg * tval;
    float nm = fmaxf(m, logit);
    float sc = __expf(m - nm);   // exp(-inf)=0 handles the first edge
    float p = __expf(logit - nm);
    s = s * sc + p;
    w = w * sc + p * msg;
    m = nm;
  }
  float outd = w / (s + 1e-16f) + zn;  // empty segment -> 0 + zn, matches ref
  float* so = sh[wv];
  so[d] = outd;
  // y = out @ W1 + b1  (64 -> 128), lane handles j=d and j=d+64
  float y0 = b1[d], y1 = b1[64 + d];
#pragma unroll 8
  for (int dd = 0; dd < 64; ++dd) {
    float o = so[dd];
    y0 = fmaf(o, W1[dd * 128 + d], y0);
    y1 = fmaf(o, W1[dd * 128 + 64 + d], y1);
  }
  // LN over 128 + relu
  float mu = wred(y0 + y1) * (1.f / 128.f);
  float d0 = y0 - mu, d1 = y1 - mu;
  float var = wred(d0 * d0 + d1 * d1) * (1.f / 128.f);
  float r = rsqrtf(var + 1e-5f);
  float z0 = fmaxf(d0 * r * g1[d] + bb1[d], 0.f);
  float z1 = fmaxf(d1 * r * g1[64 + d] + bb1[64 + d], 0.f);
  so[d] = z0;
  so[64 + d] = z1;
  // o2 = z @ W2 + b2  (128 -> 64)
  float o2 = b2[d];
#pragma unroll 8
  for (int j = 0; j < 128; ++j) o2 = fmaf(so[j], W2[j * 64 + d], o2);
  if (RESID)
    hbuf[(size_t)n * 64 + d] += o2;
  else
    hbuf[(size_t)n * 64 + d] = o2;
}

// out = relu(LN(h; ln_g[0], ln_b[0])) @ lin_W + lin_b, stored as float32
__global__ void final_kernel(const float* __restrict__ h, const float* __restrict__ g,
                             const float* __restrict__ b, const float* __restrict__ linW,
                             const float* __restrict__ linb, float* __restrict__ out,
                             int N) {
  __shared__ float sh[WPB][64];
  int wv = threadIdx.x >> 6, ln = threadIdx.x & 63;
  int n = blockIdx.x * WPB + wv;
  if (n >= N) return;
  float v = h[(size_t)n * 64 + ln];
  float mu = wred(v) * (1.f / 64.f);
  float dd = v - mu;
  float var = wred(dd * dd) * (1.f / 64.f);
  float r = rsqrtf(var + 1e-5f);
  float val = fmaxf(dd * r * g[ln] + b[ln], 0.f);
  sh[wv][ln] = val;
  float a0 = linb[ln];
  float a1 = (ln < 48) ? linb[64 + ln] : 0.f;
#pragma unroll 8
  for (int k = 0; k < 64; ++k) {
    float xv = sh[wv][k];
    a0 = fmaf(xv, linW[k * 112 + ln], a0);
    if (ln < 48) a1 = fmaf(xv, linW[k * 112 + 64 + ln], a1);
  }
  size_t base = (size_t)n * 112;
  out[base + ln] = a0;
  if (ln < 48) out[base + 64 + ln] = a1;
}

extern "C" void kernel_launch(void* const* d_in, const int* in_sizes, int n_in, void* d_out,
                              int out_size, void* d_ws, size_t ws_size, hipStream_t stream) {
  const float* x = (const float*)d_in[0];
  const float* eattr = (const float*)d_in[1];
  const int* ei = (const int*)d_in[2];
  const float* node_W = (const float*)d_in[3];
  const float* node_b = (const float*)d_in[4];
  const float* edge_W = (const float*)d_in[5];
  const float* edge_b = (const float*)d_in[6];
  const float* tptr = (const float*)d_in[7];
  const float* W1 = (const float*)d_in[8];
  const float* b1 = (const float*)d_in[9];
  const float* g1 = (const float*)d_in[10];
  const float* bb1 = (const float*)d_in[11];
  const float* W2 = (const float*)d_in[12];
  const float* b2 = (const float*)d_in[13];
  const float* lng = (const float*)d_in[14];
  const float* lnb = (const float*)d_in[15];
  const float* linW = (const float*)d_in[16];
  const float* linb = (const float*)d_in[17];
  const int N = in_sizes[0] / 8;
  const int E = in_sizes[1] / 8;
  const int* srcp = ei;
  const int* dstp = ei + E;

  char* ws = (char*)d_ws;
  size_t o = 0;
  auto alloc = [&](size_t bytes) {
    void* p = ws + o;
    o += (bytes + 255) & ~(size_t)255;
    return p;
  };
  int* off = (int*)alloc((size_t)(N + 1) * 4);
  int* cnt = (int*)alloc((size_t)N * 4);
  int* csr_src = (int*)alloc((size_t)E * 4);
  int* csr_edge = (int*)alloc((size_t)E * 4);
  float* zbuf = (float*)alloc((size_t)N * 64 * 4);
  float* hbuf = (float*)alloc((size_t)N * 64 * 4);

  int nbn = (N + WPB - 1) / WPB;

  node_enc_kernel<<<(N * 64 + 255) / 256, 256, 0, stream>>>(x, node_W, node_b, zbuf, N);
  hipMemsetAsync(cnt, 0, (size_t)N * 4, stream);
  hist_kernel<<<(E + 255) / 256, 256, 0, stream>>>(dstp, cnt, E);
  scan_kernel<<<1, 1024, 0, stream>>>(cnt, off, N);
  hipMemsetAsync(cnt, 0, (size_t)N * 4, stream);
  scatter_kernel<<<(E + 255) / 256, 256, 0, stream>>>(srcp, dstp, off, cnt, csr_src, csr_edge, E);

  conv_kernel<0><<<nbn, 256, 0, stream>>>(zbuf, hbuf, off, csr_src, csr_edge, eattr, edge_W,
                                          edge_b, tptr, 0, W1, b1, g1, bb1, W2, b2, N);
  for (int l = 1; l < 5; ++l) {
    preln_kernel<<<nbn, 256, 0, stream>>>(hbuf, zbuf, lng + l * 64, lnb + l * 64, N);
    conv_kernel<1><<<nbn, 256, 0, stream>>>(zbuf, hbuf, off, csr_src, csr_edge, eattr, edge_W,
                                            edge_b, tptr, l, W1 + l * 64 * 128, b1 + l * 128,
                                            g1 + l * 128, bb1 + l * 128, W2 + l * 128 * 64,
                                            b2 + l * 64, N);
  }
  final_kernel<<<nbn, 256, 0, stream>>>(hbuf, lng, lnb, linW, linb, (float*)d_out, N);
}

// Round 3
// 1012.565 us; speedup vs baseline: 1.1684x; 1.1684x over previous
//
#include <hip/hip_runtime.h>
#include <hip/hip_bf16.h>

#define WPB 4  // waves per block

static __device__ __forceinline__ float wred(float v) {
#pragma unroll
  for (int o = 32; o > 0; o >>= 1) v += __shfl_xor(v, o, 64);
  return v;
}

// h0[n,d] = x[n,:8] @ node_W[:,d] + node_b[d]
__global__ void node_enc_kernel(const float* __restrict__ x, const float* __restrict__ W,
                                const float* __restrict__ b, float* __restrict__ z, int N) {
  int t = blockIdx.x * blockDim.x + threadIdx.x;
  if (t >= N * 64) return;
  int n = t >> 6, d = t & 63;
  float acc = b[d];
#pragma unroll
  for (int k = 0; k < 8; ++k) acc = fmaf(x[n * 8 + k], W[k * 64 + d], acc);
  z[t] = acc;
}

__global__ void hist_kernel(const int* __restrict__ dst, int* __restrict__ cnt, int E) {
  int e = blockIdx.x * blockDim.x + threadIdx.x;
  if (e < E) atomicAdd(&cnt[dst[e]], 1);
}

// --- multi-block exclusive scan of cnt[0..n) -> off[0..n] ---
__global__ void scanA_kernel(const int* __restrict__ cnt, int* __restrict__ off,
                             int* __restrict__ bsum, int n) {
  __shared__ int lds[1024];
  int tid = threadIdx.x;
  int i = blockIdx.x * 1024 + tid;
  int v = (i < n) ? cnt[i] : 0;
  lds[tid] = v;
  __syncthreads();
  for (int ofs = 1; ofs < 1024; ofs <<= 1) {
    int tv = (tid >= ofs) ? lds[tid - ofs] : 0;
    __syncthreads();
    lds[tid] += tv;
    __syncthreads();
  }
  if (i < n) off[i] = lds[tid] - v;  // local exclusive
  if (tid == 1023) bsum[blockIdx.x] = lds[1023];
}

__global__ void scanB_kernel(const int* __restrict__ bsum, int* __restrict__ boff, int nb) {
  if (threadIdx.x == 0) {
    int acc = 0;
    for (int i = 0; i < nb; ++i) {
      boff[i] = acc;
      acc += bsum[i];
    }
    boff[nb] = acc;
  }
}

__global__ void scanC_kernel(int* __restrict__ off, const int* __restrict__ boff, int n, int nb) {
  int i = blockIdx.x * blockDim.x + threadIdx.x;
  if (i < n)
    off[i] += boff[i >> 10];
  else if (i == n)
    off[n] = boff[nb];
}

// scatter src ids into CSR; also permute edge_attr rows into CSR order (ecsr).
template <int ECSR>
__global__ void scatter_kernel(const int* __restrict__ src, const int* __restrict__ dst,
                               const int* __restrict__ off, int* __restrict__ cur,
                               int* __restrict__ csr_src, int* __restrict__ csr_edge,
                               const float* __restrict__ edge_attr, float* __restrict__ ecsr,
                               int E) {
  int e = blockIdx.x * blockDim.x + threadIdx.x;
  if (e >= E) return;
  int dn = dst[e];
  int pos = atomicAdd(&cur[dn], 1);
  int idx = off[dn] + pos;
  csr_src[idx] = src[e];
  if (ECSR) {
    const float4* ap = reinterpret_cast<const float4*>(edge_attr + (size_t)e * 8);
    float4 a0 = ap[0], a1 = ap[1];
    float4* op = reinterpret_cast<float4*>(ecsr + (size_t)idx * 8);
    op[0] = a0;
    op[1] = a1;
  } else {
    csr_edge[idx] = e;
  }
}

// z = relu(LN(h; g, b)), one wave per node, lane = channel
__global__ void preln_kernel(const float* __restrict__ h, float* __restrict__ z,
                             const float* __restrict__ g, const float* __restrict__ b, int N) {
  int wv = threadIdx.x >> 6, ln = threadIdx.x & 63;
  int n = blockIdx.x * WPB + wv;
  if (n >= N) return;
  float v = h[n * 64 + ln];
  float mu = wred(v) * (1.f / 64.f);
  float dd = v - mu;
  float var = wred(dd * dd) * (1.f / 64.f);
  float r = rsqrtf(var + 1e-5f);
  z[n * 64 + ln] = fmaxf(dd * r * g[ln] + b[ln], 0.f);
}

#define EA8(dst, A, B)                                                    \
  {                                                                       \
    dst = ebd;                                                            \
    dst = fmaf(A.x, eW[0], dst); dst = fmaf(A.y, eW[1], dst);             \
    dst = fmaf(A.z, eW[2], dst); dst = fmaf(A.w, eW[3], dst);             \
    dst = fmaf(B.x, eW[4], dst); dst = fmaf(B.y, eW[5], dst);             \
    dst = fmaf(B.z, eW[6], dst); dst = fmaf(B.w, eW[7], dst);             \
  }

// One wave per node: online-softmax aggregation over in-edges + fused 64->128->64 MLP.
// ECSR: edge features pre-permuted into CSR order (sequential reads).
template <int RESID, int ECSR>
__global__ void conv_kernel(const float* __restrict__ zbuf, float* __restrict__ hbuf,
                            const int* __restrict__ off, const int* __restrict__ csr_src,
                            const int* __restrict__ csr_edge, const float* __restrict__ efeat,
                            const float* __restrict__ edge_W, const float* __restrict__ edge_b,
                            const float* __restrict__ tptr, int layer,
                            const float* __restrict__ W1, const float* __restrict__ b1,
                            const float* __restrict__ g1, const float* __restrict__ bb1,
                            const float* __restrict__ W2, const float* __restrict__ b2, int N) {
  __shared__ float sh[WPB][128];
  int wv = threadIdx.x >> 6, d = threadIdx.x & 63;
  int n = blockIdx.x * WPB + wv;
  if (n >= N) return;
  float eW[8];
#pragma unroll
  for (int k = 0; k < 8; ++k) eW[k] = edge_W[k * 64 + d];
  float ebd = edge_b[d];
  float tval = tptr[layer];
  float zn = zbuf[n * 64 + d];
  int beg = off[n], end = off[n + 1];
  float m = -__builtin_inff(), s = 0.f, w = 0.f;
  int i = beg;
  if (ECSR) {
    for (; i + 4 <= end; i += 4) {
      int sn0 = csr_src[i], sn1 = csr_src[i + 1], sn2 = csr_src[i + 2], sn3 = csr_src[i + 3];
      const float4* ap = reinterpret_cast<const float4*>(efeat + (size_t)i * 8);
      float4 a00 = ap[0], a01 = ap[1];
      float4 a10 = ap[2], a11 = ap[3];
      float4 a20 = ap[4], a21 = ap[5];
      float4 a30 = ap[6], a31 = ap[7];
      float zs0 = zbuf[(size_t)sn0 * 64 + d];
      float zs1 = zbuf[(size_t)sn1 * 64 + d];
      float zs2 = zbuf[(size_t)sn2 * 64 + d];
      float zs3 = zbuf[(size_t)sn3 * 64 + d];
      float ea0, ea1, ea2, ea3;
      EA8(ea0, a00, a01);
      EA8(ea1, a10, a11);
      EA8(ea2, a20, a21);
      EA8(ea3, a30, a31);
      float ms0 = fmaxf(zs0 + ea0, 0.f) + 1e-7f;
      float ms1 = fmaxf(zs1 + ea1, 0.f) + 1e-7f;
      float ms2 = fmaxf(zs2 + ea2, 0.f) + 1e-7f;
      float ms3 = fmaxf(zs3 + ea3, 0.f) + 1e-7f;
      float l0 = ms0 * tval, l1 = ms1 * tval, l2 = ms2 * tval, l3 = ms3 * tval;
      float bm = fmaxf(fmaxf(l0, l1), fmaxf(l2, l3));
      float nm = fmaxf(m, bm);
      float sc = __expf(m - nm);
      float p0 = __expf(l0 - nm), p1 = __expf(l1 - nm);
      float p2 = __expf(l2 - nm), p3 = __expf(l3 - nm);
      s = fmaf(s, sc, (p0 + p1) + (p2 + p3));
      w = fmaf(w, sc, fmaf(p0, ms0, p1 * ms1) + fmaf(p2, ms2, p3 * ms3));
      m = nm;
    }
  }
  for (; i < end; ++i) {
    int sn = csr_src[i];
    const float4* ap;
    if (ECSR) {
      ap = reinterpret_cast<const float4*>(efeat + (size_t)i * 8);
    } else {
      int e = csr_edge[i];
      ap = reinterpret_cast<const float4*>(efeat + (size_t)e * 8);
    }
    float4 a0 = ap[0], a1 = ap[1];
    float zs = zbuf[(size_t)sn * 64 + d];
    float ea;
    EA8(ea, a0, a1);
    float msg = fmaxf(zs + ea, 0.f) + 1e-7f;
    float logit = msg * tval;
    float nm = fmaxf(m, logit);
    float sc = __expf(m - nm);  // exp(-inf)=0 handles the first edge
    float p = __expf(logit - nm);
    s = fmaf(s, sc, p);
    w = fmaf(w, sc, p * msg);
    m = nm;
  }
  float outd = w / (s + 1e-16f) + zn;  // empty segment -> 0 + zn, matches ref
  float* so = sh[wv];
  so[d] = outd;
  // y = out @ W1 + b1  (64 -> 128), lane handles j=d and j=d+64
  float y0 = b1[d], y1 = b1[64 + d];
#pragma unroll 8
  for (int dd = 0; dd < 64; ++dd) {
    float o = so[dd];
    y0 = fmaf(o, W1[dd * 128 + d], y0);
    y1 = fmaf(o, W1[dd * 128 + 64 + d], y1);
  }
  // LN over 128 + relu
  float mu = wred(y0 + y1) * (1.f / 128.f);
  float d0 = y0 - mu, d1 = y1 - mu;
  float var = wred(d0 * d0 + d1 * d1) * (1.f / 128.f);
  float r = rsqrtf(var + 1e-5f);
  float z0 = fmaxf(d0 * r * g1[d] + bb1[d], 0.f);
  float z1 = fmaxf(d1 * r * g1[64 + d] + bb1[64 + d], 0.f);
  so[d] = z0;
  so[64 + d] = z1;
  // o2 = z @ W2 + b2  (128 -> 64)
  float o2 = b2[d];
#pragma unroll 8
  for (int j = 0; j < 128; ++j) o2 = fmaf(so[j], W2[j * 64 + d], o2);
  if (RESID)
    hbuf[(size_t)n * 64 + d] += o2;
  else
    hbuf[(size_t)n * 64 + d] = o2;
}

// out = relu(LN(h; ln_g[0], ln_b[0])) @ lin_W + lin_b, stored as float32
__global__ void final_kernel(const float* __restrict__ h, const float* __restrict__ g,
                             const float* __restrict__ b, const float* __restrict__ linW,
                             const float* __restrict__ linb, float* __restrict__ out, int N) {
  __shared__ float sh[WPB][64];
  int wv = threadIdx.x >> 6, ln = threadIdx.x & 63;
  int n = blockIdx.x * WPB + wv;
  if (n >= N) return;
  float v = h[(size_t)n * 64 + ln];
  float mu = wred(v) * (1.f / 64.f);
  float dd = v - mu;
  float var = wred(dd * dd) * (1.f / 64.f);
  float r = rsqrtf(var + 1e-5f);
  float val = fmaxf(dd * r * g[ln] + b[ln], 0.f);
  sh[wv][ln] = val;
  float a0 = linb[ln];
  float a1 = (ln < 48) ? linb[64 + ln] : 0.f;
#pragma unroll 8
  for (int k = 0; k < 64; ++k) {
    float xv = sh[wv][k];
    a0 = fmaf(xv, linW[k * 112 + ln], a0);
    if (ln < 48) a1 = fmaf(xv, linW[k * 112 + 64 + ln], a1);
  }
  size_t base = (size_t)n * 112;
  out[base + ln] = a0;
  if (ln < 48) out[base + 64 + ln] = a1;
}

extern "C" void kernel_launch(void* const* d_in, const int* in_sizes, int n_in, void* d_out,
                              int out_size, void* d_ws, size_t ws_size, hipStream_t stream) {
  const float* x = (const float*)d_in[0];
  const float* eattr = (const float*)d_in[1];
  const int* ei = (const int*)d_in[2];
  const float* node_W = (const float*)d_in[3];
  const float* node_b = (const float*)d_in[4];
  const float* edge_W = (const float*)d_in[5];
  const float* edge_b = (const float*)d_in[6];
  const float* tptr = (const float*)d_in[7];
  const float* W1 = (const float*)d_in[8];
  const float* b1 = (const float*)d_in[9];
  const float* g1 = (const float*)d_in[10];
  const float* bb1 = (const float*)d_in[11];
  const float* W2 = (const float*)d_in[12];
  const float* b2 = (const float*)d_in[13];
  const float* lng = (const float*)d_in[14];
  const float* lnb = (const float*)d_in[15];
  const float* linW = (const float*)d_in[16];
  const float* linb = (const float*)d_in[17];
  const int N = in_sizes[0] / 8;
  const int E = in_sizes[1] / 8;
  const int* srcp = ei;
  const int* dstp = ei + E;

  char* ws = (char*)d_ws;
  size_t o = 0;
  auto alloc = [&](size_t bytes) {
    void* p = ws + o;
    o += (bytes + 255) & ~(size_t)255;
    return p;
  };
  const int nb = (N + 1023) / 1024;
  int* off = (int*)alloc((size_t)(N + 1) * 4);
  int* cnt = (int*)alloc((size_t)N * 4);
  int* bsum = (int*)alloc((size_t)nb * 4);
  int* boff = (int*)alloc((size_t)(nb + 1) * 4);
  int* csr_src = (int*)alloc((size_t)E * 4);
  float* zbuf = (float*)alloc((size_t)N * 64 * 4);
  float* hbuf = (float*)alloc((size_t)N * 64 * 4);
  // fast path needs E*8 floats for CSR-ordered edge features
  size_t need_ecsr = o + (((size_t)E * 8 * 4 + 255) & ~(size_t)255);
  int use_ecsr = (need_ecsr <= ws_size) ? 1 : 0;
  float* ecsr = nullptr;
  int* csr_edge = nullptr;
  if (use_ecsr)
    ecsr = (float*)alloc((size_t)E * 8 * 4);
  else
    csr_edge = (int*)alloc((size_t)E * 4);

  int nbn = (N + WPB - 1) / WPB;

  node_enc_kernel<<<(N * 64 + 255) / 256, 256, 0, stream>>>(x, node_W, node_b, zbuf, N);
  hipMemsetAsync(cnt, 0, (size_t)N * 4, stream);
  hist_kernel<<<(E + 255) / 256, 256, 0, stream>>>(dstp, cnt, E);
  scanA_kernel<<<nb, 1024, 0, stream>>>(cnt, off, bsum, N);
  scanB_kernel<<<1, 64, 0, stream>>>(bsum, boff, nb);
  scanC_kernel<<<(N + 1 + 255) / 256, 256, 0, stream>>>(off, boff, N, nb);
  hipMemsetAsync(cnt, 0, (size_t)N * 4, stream);
  if (use_ecsr)
    scatter_kernel<1><<<(E + 255) / 256, 256, 0, stream>>>(srcp, dstp, off, cnt, csr_src,
                                                           csr_edge, eattr, ecsr, E);
  else
    scatter_kernel<0><<<(E + 255) / 256, 256, 0, stream>>>(srcp, dstp, off, cnt, csr_src,
                                                           csr_edge, eattr, ecsr, E);

#define CONV(RES, l)                                                                        \
  do {                                                                                      \
    if (use_ecsr)                                                                           \
      conv_kernel<RES, 1><<<nbn, 256, 0, stream>>>(                                         \
          zbuf, hbuf, off, csr_src, csr_edge, ecsr, edge_W, edge_b, tptr, l,                \
          W1 + (l)*64 * 128, b1 + (l)*128, g1 + (l)*128, bb1 + (l)*128, W2 + (l)*128 * 64,  \
          b2 + (l)*64, N);                                                                  \
    else                                                                                    \
      conv_kernel<RES, 0><<<nbn, 256, 0, stream>>>(                                         \
          zbuf, hbuf, off, csr_src, csr_edge, eattr, edge_W, edge_b, tptr, l,               \
          W1 + (l)*64 * 128, b1 + (l)*128, g1 + (l)*128, bb1 + (l)*128, W2 + (l)*128 * 64,  \
          b2 + (l)*64, N);                                                                  \
  } while (0)

  CONV(0, 0);
  for (int l = 1; l < 5; ++l) {
    preln_kernel<<<nbn, 256, 0, stream>>>(hbuf, zbuf, lng + l * 64, lnb + l * 64, N);
    CONV(1, l);
  }
  final_kernel<<<nbn, 256, 0, stream>>>(hbuf, lng, lnb, linW, linb, (float*)d_out, N);
}

// Round 4
// 898.386 us; speedup vs baseline: 1.3169x; 1.1271x over previous
//
#include <hip/hip_runtime.h>
#include <hip/hip_bf16.h>
#include <hip/hip_fp16.h>

#define WPB 4  // waves per block

struct __align__(16) H8 { __half2 h[4]; };  // 8 fp16 edge features

static __device__ __forceinline__ float wred(float v) {
#pragma unroll
  for (int o = 32; o > 0; o >>= 1) v += __shfl_xor(v, o, 64);
  return v;
}

static __device__ __forceinline__ float ea_of(const H8& f, const float (&eW)[8], float ebd) {
  float2 q0 = __half22float2(f.h[0]);
  float2 q1 = __half22float2(f.h[1]);
  float2 q2 = __half22float2(f.h[2]);
  float2 q3 = __half22float2(f.h[3]);
  float ea = ebd;
  ea = fmaf(q0.x, eW[0], ea); ea = fmaf(q0.y, eW[1], ea);
  ea = fmaf(q1.x, eW[2], ea); ea = fmaf(q1.y, eW[3], ea);
  ea = fmaf(q2.x, eW[4], ea); ea = fmaf(q2.y, eW[5], ea);
  ea = fmaf(q3.x, eW[6], ea); ea = fmaf(q3.y, eW[7], ea);
  return ea;
}

// h0[n,d] = x[n,:8] @ node_W[:,d] + node_b[d], stored fp16
__global__ void node_enc_kernel(const float* __restrict__ x, const float* __restrict__ W,
                                const float* __restrict__ b, __half* __restrict__ z, int N) {
  int t = blockIdx.x * blockDim.x + threadIdx.x;
  if (t >= N * 64) return;
  int n = t >> 6, d = t & 63;
  float acc = b[d];
#pragma unroll
  for (int k = 0; k < 8; ++k) acc = fmaf(x[n * 8 + k], W[k * 64 + d], acc);
  z[t] = __float2half(acc);
}

__global__ void hist_kernel(const int* __restrict__ dst, int* __restrict__ cnt, int E) {
  int e = blockIdx.x * blockDim.x + threadIdx.x;
  if (e < E) atomicAdd(&cnt[dst[e]], 1);
}

// --- multi-block exclusive scan of cnt[0..n) -> off[0..n] ---
__global__ void scanA_kernel(const int* __restrict__ cnt, int* __restrict__ off,
                             int* __restrict__ bsum, int n) {
  __shared__ int lds[1024];
  int tid = threadIdx.x;
  int i = blockIdx.x * 1024 + tid;
  int v = (i < n) ? cnt[i] : 0;
  lds[tid] = v;
  __syncthreads();
  for (int ofs = 1; ofs < 1024; ofs <<= 1) {
    int tv = (tid >= ofs) ? lds[tid - ofs] : 0;
    __syncthreads();
    lds[tid] += tv;
    __syncthreads();
  }
  if (i < n) off[i] = lds[tid] - v;  // local exclusive
  if (tid == 1023) bsum[blockIdx.x] = lds[1023];
}

__global__ void scanB_kernel(const int* __restrict__ bsum, int* __restrict__ boff, int nb) {
  if (threadIdx.x == 0) {
    int acc = 0;
    for (int i = 0; i < nb; ++i) {
      boff[i] = acc;
      acc += bsum[i];
    }
    boff[nb] = acc;
  }
}

__global__ void scanC_kernel(int* __restrict__ off, const int* __restrict__ boff, int n, int nb) {
  int i = blockIdx.x * blockDim.x + threadIdx.x;
  if (i < n)
    off[i] += boff[i >> 10];
  else if (i == n)
    off[n] = boff[nb];
}

// scatter src ids into CSR; permute edge_attr rows into CSR order as fp16.
__global__ void scatter_kernel(const int* __restrict__ src, const int* __restrict__ dst,
                               const int* __restrict__ off, int* __restrict__ cur,
                               int* __restrict__ csr_src, const float* __restrict__ edge_attr,
                               H8* __restrict__ ecsr, int E) {
  int e = blockIdx.x * blockDim.x + threadIdx.x;
  if (e >= E) return;
  int dn = dst[e];
  int pos = atomicAdd(&cur[dn], 1);
  int idx = off[dn] + pos;
  csr_src[idx] = src[e];
  const float4* ap = reinterpret_cast<const float4*>(edge_attr + (size_t)e * 8);
  float4 a0 = ap[0], a1 = ap[1];
  H8 o;
  o.h[0] = __floats2half2_rn(a0.x, a0.y);
  o.h[1] = __floats2half2_rn(a0.z, a0.w);
  o.h[2] = __floats2half2_rn(a1.x, a1.y);
  o.h[3] = __floats2half2_rn(a1.z, a1.w);
  ecsr[idx] = o;
}

// One wave per node: online-softmax over in-edges (prefetched) + fused 64->128->64 MLP
// + fused next-layer relu(LN) written to the ping-pong fp16 buffer.
template <int RESID, int LASTL>
__global__ __launch_bounds__(256, 8) void conv_kernel(
    const __half* __restrict__ zin, __half* __restrict__ zout, float* __restrict__ hbuf,
    const int* __restrict__ off, const int* __restrict__ csr_src, const H8* __restrict__ ef,
    const float* __restrict__ edge_W, const float* __restrict__ edge_b,
    const float* __restrict__ tptr, int layer, const float* __restrict__ W1,
    const float* __restrict__ b1, const float* __restrict__ g1, const float* __restrict__ bb1,
    const float* __restrict__ W2, const float* __restrict__ b2,
    const float* __restrict__ nlg, const float* __restrict__ nlb, int N) {
  __shared__ float sh[WPB][128];
  int wv = threadIdx.x >> 6, d = threadIdx.x & 63;
  int n = blockIdx.x * WPB + wv;
  if (n >= N) return;
  float eW[8];
#pragma unroll
  for (int k = 0; k < 8; ++k) eW[k] = edge_W[k * 64 + d];
  float ebd = edge_b[d];
  float tval = tptr[layer];
  float zn = __half2float(zin[(size_t)n * 64 + d]);
  int beg = off[n], end = off[n + 1];
  int deg = end - beg;
  float m = -__builtin_inff(), s = 0.f, w = 0.f;

  for (int base = 0; base < deg; base += 64) {
    int rem = min(64, deg - base);
    int ebase = beg + base;
    int sn_l = (d < rem) ? csr_src[ebase + d] : 0;  // one coalesced load per chunk
    {  // warm the cache for this chunk's edge features (one coalesced touch)
      float tch = *reinterpret_cast<const float*>(ef + ebase + ((d < rem) ? d : rem - 1));
      asm volatile("" ::"v"(tch));
    }
    int B = (rem + 3) >> 2;
    int c0 = __shfl(sn_l, 0), c1 = __shfl(sn_l, 1), c2 = __shfl(sn_l, 2), c3 = __shfl(sn_l, 3);
    float zc0 = __half2float(zin[(size_t)c0 * 64 + d]);
    float zc1 = __half2float(zin[(size_t)c1 * 64 + d]);
    float zc2 = __half2float(zin[(size_t)c2 * 64 + d]);
    float zc3 = __half2float(zin[(size_t)c3 * 64 + d]);
    for (int b = 0; b < B; ++b) {
      int n0 = 0, n1 = 0, n2 = 0, n3 = 0;
      float zf0 = 0.f, zf1 = 0.f, zf2 = 0.f, zf3 = 0.f;
      bool more = (b + 1 < B);
      if (more) {  // prefetch next batch's gathers while current computes
        int l4 = 4 * b + 4;
        n0 = __shfl(sn_l, l4); n1 = __shfl(sn_l, l4 + 1);
        n2 = __shfl(sn_l, l4 + 2); n3 = __shfl(sn_l, l4 + 3);
        zf0 = __half2float(zin[(size_t)n0 * 64 + d]);
        zf1 = __half2float(zin[(size_t)n1 * 64 + d]);
        zf2 = __half2float(zin[(size_t)n2 * 64 + d]);
        zf3 = __half2float(zin[(size_t)n3 * 64 + d]);
      }
      int r4 = rem - 4 * b;  // >= 1
      int e0 = ebase + 4 * b;
      H8 f0 = ef[e0];
      float ea0 = ea_of(f0, eW, ebd);
      H8 f1 = ef[e0 + min(1, r4 - 1)];
      float ea1 = ea_of(f1, eW, ebd);
      H8 f2 = ef[e0 + min(2, r4 - 1)];
      float ea2 = ea_of(f2, eW, ebd);
      H8 f3 = ef[e0 + min(3, r4 - 1)];
      float ea3 = ea_of(f3, eW, ebd);
      float ms0 = fmaxf(zc0 + ea0, 0.f) + 1e-7f;
      float ms1 = fmaxf(zc1 + ea1, 0.f) + 1e-7f;
      float ms2 = fmaxf(zc2 + ea2, 0.f) + 1e-7f;
      float ms3 = fmaxf(zc3 + ea3, 0.f) + 1e-7f;
      float l0 = ms0 * tval, l1 = ms1 * tval, l2 = ms2 * tval, l3 = ms3 * tval;
      if (r4 < 4) {  // uniform, rare: mask tail edges
        if (r4 < 2) l1 = -__builtin_inff();
        if (r4 < 3) l2 = -__builtin_inff();
        l3 = -__builtin_inff();
      }
      float bm = fmaxf(fmaxf(l0, l1), fmaxf(l2, l3));
      float nm = fmaxf(m, bm);
      float sc = __expf(m - nm);  // exp(-inf)=0 on first batch
      float p0 = __expf(l0 - nm), p1 = __expf(l1 - nm);
      float p2 = __expf(l2 - nm), p3 = __expf(l3 - nm);
      s = fmaf(s, sc, (p0 + p1) + (p2 + p3));
      w = fmaf(w, sc, fmaf(p0, ms0, p1 * ms1) + fmaf(p2, ms2, p3 * ms3));
      m = nm;
      if (more) {
        c0 = n0; c1 = n1; c2 = n2; c3 = n3;
        zc0 = zf0; zc1 = zf1; zc2 = zf2; zc3 = zf3;
      }
    }
  }
  float outd = w / (s + 1e-16f) + zn;  // empty segment -> zn, matches ref

  float* so = sh[wv];
  so[d] = outd;
  const float4* so4 = reinterpret_cast<const float4*>(so);
  // y = out @ W1 + b1  (64 -> 128)
  float y0 = b1[d], y1 = b1[64 + d];
#pragma unroll
  for (int q = 0; q < 16; ++q) {
    float4 ov = so4[q];
    int dd = q * 4;
    y0 = fmaf(ov.x, W1[(dd + 0) * 128 + d], y0); y1 = fmaf(ov.x, W1[(dd + 0) * 128 + 64 + d], y1);
    y0 = fmaf(ov.y, W1[(dd + 1) * 128 + d], y0); y1 = fmaf(ov.y, W1[(dd + 1) * 128 + 64 + d], y1);
    y0 = fmaf(ov.z, W1[(dd + 2) * 128 + d], y0); y1 = fmaf(ov.z, W1[(dd + 2) * 128 + 64 + d], y1);
    y0 = fmaf(ov.w, W1[(dd + 3) * 128 + d], y0); y1 = fmaf(ov.w, W1[(dd + 3) * 128 + 64 + d], y1);
  }
  // LN over 128 + relu
  float mu = wred(y0 + y1) * (1.f / 128.f);
  float d0 = y0 - mu, d1 = y1 - mu;
  float var = wred(d0 * d0 + d1 * d1) * (1.f / 128.f);
  float r = rsqrtf(var + 1e-5f);
  float z0 = fmaxf(d0 * r * g1[d] + bb1[d], 0.f);
  float z1 = fmaxf(d1 * r * g1[64 + d] + bb1[64 + d], 0.f);
  so[d] = z0;
  so[64 + d] = z1;
  // o2 = z @ W2 + b2  (128 -> 64)
  float o2 = b2[d];
#pragma unroll
  for (int q = 0; q < 32; ++q) {
    float4 ov = so4[q];
    int j = q * 4;
    o2 = fmaf(ov.x, W2[(j + 0) * 64 + d], o2);
    o2 = fmaf(ov.y, W2[(j + 1) * 64 + d], o2);
    o2 = fmaf(ov.z, W2[(j + 2) * 64 + d], o2);
    o2 = fmaf(ov.w, W2[(j + 3) * 64 + d], o2);
  }
  float hnew = RESID ? (hbuf[(size_t)n * 64 + d] + o2) : o2;
  if (!LASTL) hbuf[(size_t)n * 64 + d] = hnew;
  // fused next-layer relu(LN) -> ping-pong fp16 buffer
  float mu2 = wred(hnew) * (1.f / 64.f);
  float dd2 = hnew - mu2;
  float var2 = wred(dd2 * dd2) * (1.f / 64.f);
  float r2 = rsqrtf(var2 + 1e-5f);
  zout[(size_t)n * 64 + d] = __float2half(fmaxf(dd2 * r2 * nlg[d] + nlb[d], 0.f));
}

// out = z @ lin_W + lin_b  (z already relu(LN)'d by conv4's epilogue)
__global__ void final_kernel(const __half* __restrict__ zh, const float* __restrict__ linW,
                             const float* __restrict__ linb, float* __restrict__ out, int N) {
  __shared__ float sh[WPB][64];
  int wv = threadIdx.x >> 6, ln = threadIdx.x & 63;
  int n = blockIdx.x * WPB + wv;
  if (n >= N) return;
  sh[wv][ln] = __half2float(zh[(size_t)n * 64 + ln]);
  float a0 = linb[ln];
  float a1 = (ln < 48) ? linb[64 + ln] : 0.f;
  const float4* s4 = reinterpret_cast<const float4*>(sh[wv]);
#pragma unroll
  for (int q = 0; q < 16; ++q) {
    float4 xv = s4[q];
    int k = q * 4;
    a0 = fmaf(xv.x, linW[(k + 0) * 112 + ln], a0);
    a0 = fmaf(xv.y, linW[(k + 1) * 112 + ln], a0);
    a0 = fmaf(xv.z, linW[(k + 2) * 112 + ln], a0);
    a0 = fmaf(xv.w, linW[(k + 3) * 112 + ln], a0);
    if (ln < 48) {
      a1 = fmaf(xv.x, linW[(k + 0) * 112 + 64 + ln], a1);
      a1 = fmaf(xv.y, linW[(k + 1) * 112 + 64 + ln], a1);
      a1 = fmaf(xv.z, linW[(k + 2) * 112 + 64 + ln], a1);
      a1 = fmaf(xv.w, linW[(k + 3) * 112 + 64 + ln], a1);
    }
  }
  size_t b = (size_t)n * 112;
  out[b + ln] = a0;
  if (ln < 48) out[b + 64 + ln] = a1;
}

extern "C" void kernel_launch(void* const* d_in, const int* in_sizes, int n_in, void* d_out,
                              int out_size, void* d_ws, size_t ws_size, hipStream_t stream) {
  const float* x = (const float*)d_in[0];
  const float* eattr = (const float*)d_in[1];
  const int* ei = (const int*)d_in[2];
  const float* node_W = (const float*)d_in[3];
  const float* node_b = (const float*)d_in[4];
  const float* edge_W = (const float*)d_in[5];
  const float* edge_b = (const float*)d_in[6];
  const float* tptr = (const float*)d_in[7];
  const float* W1 = (const float*)d_in[8];
  const float* b1 = (const float*)d_in[9];
  const float* g1 = (const float*)d_in[10];
  const float* bb1 = (const float*)d_in[11];
  const float* W2 = (const float*)d_in[12];
  const float* b2 = (const float*)d_in[13];
  const float* lng = (const float*)d_in[14];
  const float* lnb = (const float*)d_in[15];
  const float* linW = (const float*)d_in[16];
  const float* linb = (const float*)d_in[17];
  const int N = in_sizes[0] / 8;
  const int E = in_sizes[1] / 8;
  const int* srcp = ei;
  const int* dstp = ei + E;

  char* ws = (char*)d_ws;
  size_t o = 0;
  auto alloc = [&](size_t bytes) {
    void* p = ws + o;
    o += (bytes + 255) & ~(size_t)255;
    return p;
  };
  const int nb = (N + 1023) / 1024;
  int* off = (int*)alloc((size_t)(N + 1) * 4);
  int* cnt = (int*)alloc((size_t)N * 4);
  int* bsum = (int*)alloc((size_t)nb * 4);
  int* boff = (int*)alloc((size_t)(nb + 1) * 4);
  int* csr_src = (int*)alloc((size_t)E * 4);
  __half* zh0 = (__half*)alloc((size_t)N * 64 * 2);
  __half* zh1 = (__half*)alloc((size_t)N * 64 * 2);
  float* hbuf = (float*)alloc((size_t)N * 64 * 4);
  H8* ecsr = (H8*)alloc((size_t)E * 16);

  int nbn = (N + WPB - 1) / WPB;

  node_enc_kernel<<<(N * 64 + 255) / 256, 256, 0, stream>>>(x, node_W, node_b, zh0, N);
  hipMemsetAsync(cnt, 0, (size_t)N * 4, stream);
  hist_kernel<<<(E + 255) / 256, 256, 0, stream>>>(dstp, cnt, E);
  scanA_kernel<<<nb, 1024, 0, stream>>>(cnt, off, bsum, N);
  scanB_kernel<<<1, 64, 0, stream>>>(bsum, boff, nb);
  scanC_kernel<<<(N + 1 + 255) / 256, 256, 0, stream>>>(off, boff, N, nb);
  hipMemsetAsync(cnt, 0, (size_t)N * 4, stream);
  scatter_kernel<<<(E + 255) / 256, 256, 0, stream>>>(srcp, dstp, off, cnt, csr_src, eattr,
                                                      ecsr, E);

  const __half* zi[5] = {zh0, zh1, zh0, zh1, zh0};
  __half* zo[5] = {zh1, zh0, zh1, zh0, zh1};
#define CONVL(RES, LAST, l, NL)                                                               \
  conv_kernel<RES, LAST><<<nbn, 256, 0, stream>>>(                                            \
      zi[l], zo[l], hbuf, off, csr_src, ecsr, edge_W, edge_b, tptr, l, W1 + (l)*64 * 128,     \
      b1 + (l)*128, g1 + (l)*128, bb1 + (l)*128, W2 + (l)*128 * 64, b2 + (l)*64,              \
      lng + (NL)*64, lnb + (NL)*64, N)

  CONVL(0, 0, 0, 1);
  CONVL(1, 0, 1, 2);
  CONVL(1, 0, 2, 3);
  CONVL(1, 0, 3, 4);
  CONVL(1, 1, 4, 0);  // last conv applies layer-0 norm for the head
  final_kernel<<<nbn, 256, 0, stream>>>(zo[4], linW, linb, (float*)d_out, N);
}

// Round 5
// 769.272 us; speedup vs baseline: 1.5380x; 1.1678x over previous
//
#include <hip/hip_runtime.h>
#include <hip/hip_fp16.h>

#define WPB 4    // waves (nodes) per block
#define CHUNK 32 // edges staged to LDS per iteration

static __device__ __forceinline__ void gload_lds4(const void* gp, void* lp) {
  __builtin_amdgcn_global_load_lds((const __attribute__((address_space(1))) void*)gp,
                                   (__attribute__((address_space(3))) void*)lp, 4, 0, 0);
}

static __device__ __forceinline__ float wred(float v) {
#pragma unroll
  for (int o = 32; o > 0; o >>= 1) v += __shfl_xor(v, o, 64);
  return v;
}

static __device__ __forceinline__ float ea8(float4 u, float4 v, const float (&eW)[8],
                                            float ebd) {
  float ea = ebd;
  ea = fmaf(u.x, eW[0], ea); ea = fmaf(u.y, eW[1], ea);
  ea = fmaf(u.z, eW[2], ea); ea = fmaf(u.w, eW[3], ea);
  ea = fmaf(v.x, eW[4], ea); ea = fmaf(v.y, eW[5], ea);
  ea = fmaf(v.z, eW[6], ea); ea = fmaf(v.w, eW[7], ea);
  return ea;
}

// h0[n,d] = x[n,:8] @ node_W[:,d] + node_b[d], stored fp16
__global__ void node_enc_kernel(const float* __restrict__ x, const float* __restrict__ W,
                                const float* __restrict__ b, __half* __restrict__ z, int N) {
  int t = blockIdx.x * blockDim.x + threadIdx.x;
  if (t >= N * 64) return;
  int n = t >> 6, d = t & 63;
  float acc = b[d];
#pragma unroll
  for (int k = 0; k < 8; ++k) acc = fmaf(x[n * 8 + k], W[k * 64 + d], acc);
  z[t] = __float2half(acc);
}

__global__ void hist_kernel(const int* __restrict__ dst, int* __restrict__ cnt, int E) {
  int e = blockIdx.x * blockDim.x + threadIdx.x;
  if (e < E) atomicAdd(&cnt[dst[e]], 1);
}

// --- multi-block exclusive scan of cnt[0..n) -> off[0..n] ---
__global__ void scanA_kernel(const int* __restrict__ cnt, int* __restrict__ off,
                             int* __restrict__ bsum, int n) {
  __shared__ int lds[1024];
  int tid = threadIdx.x;
  int i = blockIdx.x * 1024 + tid;
  int v = (i < n) ? cnt[i] : 0;
  lds[tid] = v;
  __syncthreads();
  for (int ofs = 1; ofs < 1024; ofs <<= 1) {
    int tv = (tid >= ofs) ? lds[tid - ofs] : 0;
    __syncthreads();
    lds[tid] += tv;
    __syncthreads();
  }
  if (i < n) off[i] = lds[tid] - v;  // local exclusive
  if (tid == 1023) bsum[blockIdx.x] = lds[1023];
}

__global__ void scanB_kernel(const int* __restrict__ bsum, int* __restrict__ boff, int nb) {
  if (threadIdx.x == 0) {
    int acc = 0;
    for (int i = 0; i < nb; ++i) {
      boff[i] = acc;
      acc += bsum[i];
    }
    boff[nb] = acc;
  }
}

__global__ void scanC_kernel(int* __restrict__ off, const int* __restrict__ boff, int n, int nb) {
  int i = blockIdx.x * blockDim.x + threadIdx.x;
  if (i < n)
    off[i] += boff[i >> 10];
  else if (i == n)
    off[n] = boff[nb];
}

// scatter src ids into CSR; permute edge_attr rows into CSR order (f32).
__global__ void scatter_kernel(const int* __restrict__ src, const int* __restrict__ dst,
                               const int* __restrict__ off, int* __restrict__ cur,
                               int* __restrict__ csr_src, const float* __restrict__ edge_attr,
                               float* __restrict__ ecsr, int E) {
  int e = blockIdx.x * blockDim.x + threadIdx.x;
  if (e >= E) return;
  int dn = dst[e];
  int pos = atomicAdd(&cur[dn], 1);
  int idx = off[dn] + pos;
  csr_src[idx] = src[e];
  const float4* ap = reinterpret_cast<const float4*>(edge_attr + (size_t)e * 8);
  float4* op = reinterpret_cast<float4*>(ecsr + (size_t)idx * 8);
  op[0] = ap[0];
  op[1] = ap[1];
}

// One wave per node: LDS-staged online-softmax over in-edges + fused 64->128->64 MLP
// + fused next-layer relu(LN) into the ping-pong fp16 buffer.
template <int RESID, int LASTL>
__global__ void conv_kernel(
    const __half* __restrict__ zin, __half* __restrict__ zout, float* __restrict__ hbuf,
    const int* __restrict__ off, const int* __restrict__ csr_src, const float* __restrict__ ef,
    const float* __restrict__ edge_W, const float* __restrict__ edge_b,
    const float* __restrict__ tptr, int layer, const float* __restrict__ W1,
    const float* __restrict__ b1, const float* __restrict__ g1, const float* __restrict__ bb1,
    const float* __restrict__ W2, const float* __restrict__ b2,
    const float* __restrict__ nlg, const float* __restrict__ nlb, int N) {
  __shared__ __half zst[WPB][CHUNK * 64];           // 4 KB/wave: staged src feature rows
  __shared__ __align__(16) float efst[WPB][CHUNK * 8];  // 1 KB/wave: staged edge features
  __shared__ float sh[WPB][128];
  int wv = threadIdx.x >> 6, d = threadIdx.x & 63;
  int n = blockIdx.x * WPB + wv;
  if (n >= N) return;
  float eW[8];
#pragma unroll
  for (int k = 0; k < 8; ++k) eW[k] = edge_W[k * 64 + d];
  float ebd = edge_b[d];
  float tval = tptr[layer];
  float zn = __half2float(zin[((size_t)n << 6) + d]);
  int beg = off[n], end = off[n + 1];
  int deg = end - beg;
  float m = -__builtin_inff(), s = 0.f, w = 0.f;
  int half = d >> 5, lane32 = d & 31;
  char* zb = (char*)&zst[wv][0];
  char* eb = (char*)&efst[wv][0];

  for (int base = 0; base < deg; base += CHUNK) {
    int rem = min(CHUNK, deg - base);
    int e0 = beg + base;
    int sn_l = csr_src[e0 + min(d, rem - 1)];  // coalesced; lane i holds src of edge i
    // stage edge features (rem*32 B, 256 B/instr; over-read covered by alloc slack)
    const char* efg = (const char*)(ef + (size_t)e0 * 8);
    int ngrp = (rem * 32 + 255) >> 8;
    for (int g = 0; g < ngrp; ++g)
      gload_lds4(efg + (g << 8) + (d << 2), eb + (g << 8));
    // stage z rows: 2 edges per instr (lanes 0-31 edge 2p, lanes 32-63 edge 2p+1)
    int npair = (rem + 1) >> 1;
    for (int p = 0; p < npair; ++p) {
      int sn = __shfl(sn_l, min(2 * p + half, rem - 1));
      const __half* gp = zin + ((size_t)sn << 6) + (lane32 << 1);
      gload_lds4(gp, zb + (p << 8));
    }
    asm volatile("s_waitcnt vmcnt(0)" ::: "memory");
    int nb4 = (rem + 3) >> 2;
    for (int b = 0; b < nb4; ++b) {
      int eo = 4 * b;
      int r4 = rem - eo;  // >= 1
      float z0 = __half2float(zst[wv][(eo + 0) * 64 + d]);
      float z1 = __half2float(zst[wv][(eo + 1) * 64 + d]);
      float z2 = __half2float(zst[wv][(eo + 2) * 64 + d]);
      float z3 = __half2float(zst[wv][(eo + 3) * 64 + d]);
      const float4* fp = reinterpret_cast<const float4*>(&efst[wv][eo * 8]);
      float ea0 = ea8(fp[0], fp[1], eW, ebd);
      float ea1 = ea8(fp[2], fp[3], eW, ebd);
      float ea2 = ea8(fp[4], fp[5], eW, ebd);
      float ea3 = ea8(fp[6], fp[7], eW, ebd);
      float ms0 = fmaxf(z0 + ea0, 0.f) + 1e-7f;
      float ms1 = fmaxf(z1 + ea1, 0.f) + 1e-7f;
      float ms2 = fmaxf(z2 + ea2, 0.f) + 1e-7f;
      float ms3 = fmaxf(z3 + ea3, 0.f) + 1e-7f;
      float l0 = ms0 * tval, l1 = ms1 * tval, l2 = ms2 * tval, l3 = ms3 * tval;
      if (r4 < 4) {  // mask tail edges (wave-uniform branch, rare)
        if (r4 < 2) l1 = -__builtin_inff();
        if (r4 < 3) l2 = -__builtin_inff();
        l3 = -__builtin_inff();
      }
      float bm = fmaxf(fmaxf(l0, l1), fmaxf(l2, l3));
      float nm = fmaxf(m, bm);
      float sc = __expf(m - nm);  // exp(-inf)=0 on first batch
      float p0 = __expf(l0 - nm), p1 = __expf(l1 - nm);
      float p2 = __expf(l2 - nm), p3 = __expf(l3 - nm);
      s = fmaf(s, sc, (p0 + p1) + (p2 + p3));
      w = fmaf(w, sc, fmaf(p0, ms0, p1 * ms1) + fmaf(p2, ms2, p3 * ms3));
      m = nm;
    }
  }
  float outd = w / (s + 1e-16f) + zn;  // empty segment -> zn, matches ref

  float* so = sh[wv];
  so[d] = outd;
  const float4* so4 = reinterpret_cast<const float4*>(so);
  // y = out @ W1 + b1  (64 -> 128)
  float y0 = b1[d], y1 = b1[64 + d];
#pragma unroll
  for (int q = 0; q < 16; ++q) {
    float4 ov = so4[q];
    int dd = q * 4;
    y0 = fmaf(ov.x, W1[(dd + 0) * 128 + d], y0); y1 = fmaf(ov.x, W1[(dd + 0) * 128 + 64 + d], y1);
    y0 = fmaf(ov.y, W1[(dd + 1) * 128 + d], y0); y1 = fmaf(ov.y, W1[(dd + 1) * 128 + 64 + d], y1);
    y0 = fmaf(ov.z, W1[(dd + 2) * 128 + d], y0); y1 = fmaf(ov.z, W1[(dd + 2) * 128 + 64 + d], y1);
    y0 = fmaf(ov.w, W1[(dd + 3) * 128 + d], y0); y1 = fmaf(ov.w, W1[(dd + 3) * 128 + 64 + d], y1);
  }
  // LN over 128 + relu
  float mu = wred(y0 + y1) * (1.f / 128.f);
  float d0 = y0 - mu, d1 = y1 - mu;
  float var = wred(d0 * d0 + d1 * d1) * (1.f / 128.f);
  float r = rsqrtf(var + 1e-5f);
  float z0v = fmaxf(d0 * r * g1[d] + bb1[d], 0.f);
  float z1v = fmaxf(d1 * r * g1[64 + d] + bb1[64 + d], 0.f);
  so[d] = z0v;
  so[64 + d] = z1v;
  // o2 = z @ W2 + b2  (128 -> 64)
  float o2 = b2[d];
#pragma unroll
  for (int q = 0; q < 32; ++q) {
    float4 ov = so4[q];
    int j = q * 4;
    o2 = fmaf(ov.x, W2[(j + 0) * 64 + d], o2);
    o2 = fmaf(ov.y, W2[(j + 1) * 64 + d], o2);
    o2 = fmaf(ov.z, W2[(j + 2) * 64 + d], o2);
    o2 = fmaf(ov.w, W2[(j + 3) * 64 + d], o2);
  }
  float hnew = RESID ? (hbuf[((size_t)n << 6) + d] + o2) : o2;
  if (!LASTL) hbuf[((size_t)n << 6) + d] = hnew;
  // fused next-layer relu(LN) -> ping-pong fp16 buffer
  float mu2 = wred(hnew) * (1.f / 64.f);
  float dd2 = hnew - mu2;
  float var2 = wred(dd2 * dd2) * (1.f / 64.f);
  float r2 = rsqrtf(var2 + 1e-5f);
  zout[((size_t)n << 6) + d] = __float2half(fmaxf(dd2 * r2 * nlg[d] + nlb[d], 0.f));
}

// out = z @ lin_W + lin_b  (z already relu(LN)'d by conv4's epilogue)
__global__ void final_kernel(const __half* __restrict__ zh, const float* __restrict__ linW,
                             const float* __restrict__ linb, float* __restrict__ out, int N) {
  __shared__ float sh[WPB][64];
  int wv = threadIdx.x >> 6, ln = threadIdx.x & 63;
  int n = blockIdx.x * WPB + wv;
  if (n >= N) return;
  sh[wv][ln] = __half2float(zh[((size_t)n << 6) + ln]);
  float a0 = linb[ln];
  float a1 = (ln < 48) ? linb[64 + ln] : 0.f;
  const float4* s4 = reinterpret_cast<const float4*>(sh[wv]);
#pragma unroll
  for (int q = 0; q < 16; ++q) {
    float4 xv = s4[q];
    int k = q * 4;
    a0 = fmaf(xv.x, linW[(k + 0) * 112 + ln], a0);
    a0 = fmaf(xv.y, linW[(k + 1) * 112 + ln], a0);
    a0 = fmaf(xv.z, linW[(k + 2) * 112 + ln], a0);
    a0 = fmaf(xv.w, linW[(k + 3) * 112 + ln], a0);
    if (ln < 48) {
      a1 = fmaf(xv.x, linW[(k + 0) * 112 + 64 + ln], a1);
      a1 = fmaf(xv.y, linW[(k + 1) * 112 + 64 + ln], a1);
      a1 = fmaf(xv.z, linW[(k + 2) * 112 + 64 + ln], a1);
      a1 = fmaf(xv.w, linW[(k + 3) * 112 + 64 + ln], a1);
    }
  }
  size_t b = (size_t)n * 112;
  out[b + ln] = a0;
  if (ln < 48) out[b + 64 + ln] = a1;
}

extern "C" void kernel_launch(void* const* d_in, const int* in_sizes, int n_in, void* d_out,
                              int out_size, void* d_ws, size_t ws_size, hipStream_t stream) {
  const float* x = (const float*)d_in[0];
  const float* eattr = (const float*)d_in[1];
  const int* ei = (const int*)d_in[2];
  const float* node_W = (const float*)d_in[3];
  const float* node_b = (const float*)d_in[4];
  const float* edge_W = (const float*)d_in[5];
  const float* edge_b = (const float*)d_in[6];
  const float* tptr = (const float*)d_in[7];
  const float* W1 = (const float*)d_in[8];
  const float* b1 = (const float*)d_in[9];
  const float* g1 = (const float*)d_in[10];
  const float* bb1 = (const float*)d_in[11];
  const float* W2 = (const float*)d_in[12];
  const float* b2 = (const float*)d_in[13];
  const float* lng = (const float*)d_in[14];
  const float* lnb = (const float*)d_in[15];
  const float* linW = (const float*)d_in[16];
  const float* linb = (const float*)d_in[17];
  const int N = in_sizes[0] / 8;
  const int E = in_sizes[1] / 8;
  const int* srcp = ei;
  const int* dstp = ei + E;

  char* ws = (char*)d_ws;
  size_t o = 0;
  auto alloc = [&](size_t bytes) {
    void* p = ws + o;
    o += (bytes + 255) & ~(size_t)255;
    return p;
  };
  const int nb = (N + 1023) / 1024;
  int* off = (int*)alloc((size_t)(N + 1) * 4);
  int* cnt = (int*)alloc((size_t)N * 4);
  int* bsum = (int*)alloc((size_t)nb * 4);
  int* boff = (int*)alloc((size_t)(nb + 1) * 4);
  int* csr_src = (int*)alloc((size_t)E * 4);
  __half* zh0 = (__half*)alloc((size_t)N * 64 * 2);
  __half* zh1 = (__half*)alloc((size_t)N * 64 * 2);
  float* hbuf = (float*)alloc((size_t)N * 64 * 4);
  float* ecsr = (float*)alloc((size_t)E * 8 * 4 + 512);  // slack for staging over-read

  int nbn = (N + WPB - 1) / WPB;

  node_enc_kernel<<<(N * 64 + 255) / 256, 256, 0, stream>>>(x, node_W, node_b, zh0, N);
  hipMemsetAsync(cnt, 0, (size_t)N * 4, stream);
  hist_kernel<<<(E + 255) / 256, 256, 0, stream>>>(dstp, cnt, E);
  scanA_kernel<<<nb, 1024, 0, stream>>>(cnt, off, bsum, N);
  scanB_kernel<<<1, 64, 0, stream>>>(bsum, boff, nb);
  scanC_kernel<<<(N + 1 + 255) / 256, 256, 0, stream>>>(off, boff, N, nb);
  hipMemsetAsync(cnt, 0, (size_t)N * 4, stream);
  scatter_kernel<<<(E + 255) / 256, 256, 0, stream>>>(srcp, dstp, off, cnt, csr_src, eattr,
                                                      ecsr, E);

  const __half* zi[5] = {zh0, zh1, zh0, zh1, zh0};
  __half* zo[5] = {zh1, zh0, zh1, zh0, zh1};
#define CONVL(RES, LAST, l, NL)                                                               \
  conv_kernel<RES, LAST><<<nbn, 256, 0, stream>>>(                                            \
      zi[l], zo[l], hbuf, off, csr_src, ecsr, edge_W, edge_b, tptr, l, W1 + (l)*64 * 128,     \
      b1 + (l)*128, g1 + (l)*128, bb1 + (l)*128, W2 + (l)*128 * 64, b2 + (l)*64,              \
      lng + (NL)*64, lnb + (NL)*64, N)

  CONVL(0, 0, 0, 1);
  CONVL(1, 0, 1, 2);
  CONVL(1, 0, 2, 3);
  CONVL(1, 0, 3, 4);
  CONVL(1, 1, 4, 0);  // last conv applies layer-0 norm for the head
  final_kernel<<<nbn, 256, 0, stream>>>(zo[4], linW, linb, (float*)d_out, N);
}